// Round 3
// baseline (1688.856 us; speedup 1.0000x reference)
//
#include <hip/hip_runtime.h>

#define TT 512   // max sequence length T
#define NN 128   // number of tags N
#define NTHR 512 // 8 waves
#define BD  64   // backtrack chunk depth
#define MAXG 8   // max chunks = ceil((TT-1)/BD)

// One block per batch element (256 blocks <-> 256 CUs).
// thread -> (j, c): j = tid>>3 in 0..63 (thread serves tags j and j+64),
// c = tid&7 owns i-range [16c, 16c+16). trans chunks in VGPRs (32 regs).
// State double-buffered in LDS; reads swizzled so each ds_read_b128 slot's 8
// distinct addresses cover all 32 banks (zero conflicts); one barrier/step.
__global__ __launch_bounds__(NTHR, 1)
void crf_viterbi_kernel(const float* __restrict__ logits,
                        const float* __restrict__ trans,
                        const int* __restrict__ seqlen,
                        int* __restrict__ out) {
    __shared__ float stateBuf[2][NN];
    __shared__ float redV[NN];
    __shared__ int   redI[NN];
    __shared__ int   tagBuf[TT];
    __shared__ int   entryTag[MAXG];
    __shared__ unsigned char bp[TT][NN];          // 64 KiB backpointers
    __shared__ unsigned char hist[MAXG][BD][NN];  // 64 KiB backtrack histories

    const int tid = threadIdx.x;
    const int j   = tid >> 3;   // 0..63 (serves j and j+64)
    const int c   = tid & 7;    // i-chunk
    const int i0  = c << 4;
    const int b   = blockIdx.x;
    const int L   = seqlen[b];  // in [1, TT]

    // Transition chunks: tr0[k] = trans[i0+k][j], tr1[k] = trans[i0+k][j+64]
    float tr0[16], tr1[16];
    #pragma unroll
    for (int k = 0; k < 16; ++k) {
        tr0[k] = trans[(i0 + k) * NN + j];
        tr1[k] = trans[(i0 + k) * NN + j + 64];
    }

    const float* lrow = logits + (size_t)b * TT * NN;

    if (c == 0) {
        stateBuf[0][j]      = lrow[j];
        stateBuf[0][j + 64] = lrow[j + 64];
    }
    __syncthreads();

    // 2-deep logits prefetch ring (rows always allocated up to TT; values
    // beyond L-1 are loaded but never used).
    float xa0 = lrow[NN + j],     xa1 = lrow[NN + j + 64];
    float xb0 = lrow[2*NN + j],   xb1 = lrow[2*NN + j + 64];
    const int rot = (c >> 1) & 3;

    int p = 0;
    for (int t = 1; t < L; ++t) {
        int tn = t + 2; tn = (tn < TT) ? tn : (TT - 1);
        float xc0 = lrow[tn * NN + j];
        float xc1 = lrow[tn * NN + j + 64];

        // Swizzled state reads: slot q reads quad (q+rot)&3 -> banks
        // 16*(c&1) + 4*((q + c/2)&3): 8 distinct bank-quads, zero conflicts.
        const float* st = stateBuf[p] + i0;
        float4 s4[4];
        #pragma unroll
        for (int q = 0; q < 4; ++q) {
            int qq = (q + rot) & 3;
            s4[qq] = *(const float4*)(st + 4 * qq);
        }
        float ss[16];
        #pragma unroll
        for (int q = 0; q < 4; ++q) {
            ss[4*q+0] = s4[q].x; ss[4*q+1] = s4[q].y;
            ss[4*q+2] = s4[q].z; ss[4*q+3] = s4[q].w;
        }
        float sc0[16], sc1[16];
        #pragma unroll
        for (int k = 0; k < 16; ++k) {
            sc0[k] = ss[k] + tr0[k];
            sc1[k] = ss[k] + tr1[k];
        }

        // In-thread argmax trees, contiguous pairing: take right only if
        // strictly greater == exact jnp first-occurrence semantics.
        float va0[8], va1[8]; int ia0[8], ia1[8];
        #pragma unroll
        for (int k = 0; k < 8; ++k) {
            bool g0 = sc0[2*k+1] > sc0[2*k];
            va0[k] = g0 ? sc0[2*k+1] : sc0[2*k];
            ia0[k] = g0 ? (2*k+1) : (2*k);
            bool g1 = sc1[2*k+1] > sc1[2*k];
            va1[k] = g1 ? sc1[2*k+1] : sc1[2*k];
            ia1[k] = g1 ? (2*k+1) : (2*k);
        }
        #pragma unroll
        for (int w = 4; w >= 1; w >>= 1) {
            #pragma unroll
            for (int k = 0; k < w; ++k) {
                bool g0 = va0[2*k+1] > va0[2*k];
                va0[k] = g0 ? va0[2*k+1] : va0[2*k];
                ia0[k] = g0 ? ia0[2*k+1] : ia0[2*k];
                bool g1 = va1[2*k+1] > va1[2*k];
                va1[k] = g1 ? va1[2*k+1] : va1[2*k];
                ia1[k] = g1 ? ia1[2*k+1] : ia1[2*k];
            }
        }
        float bv0 = va0[0], bv1 = va1[0];
        int   bi0 = i0 + ia0[0], bi1 = i0 + ia1[0];

        // Combine the 8 chunk-partials within the lane octet (same j).
        // On tie the lower-index chunk wins (exact reference semantics).
        #pragma unroll
        for (int m = 1; m <= 4; m <<= 1) {
            bool partnerLower = (c & m) != 0;
            float p0 = __shfl_xor(bv0, m, 64); int q0 = __shfl_xor(bi0, m, 64);
            float p1 = __shfl_xor(bv1, m, 64); int q1 = __shfl_xor(bi1, m, 64);
            bool t0 = (p0 > bv0) || ((p0 == bv0) && partnerLower);
            bool t1 = (p1 > bv1) || ((p1 == bv1) && partnerLower);
            bv0 = t0 ? p0 : bv0;  bi0 = t0 ? q0 : bi0;
            bv1 = t1 ? p1 : bv1;  bi1 = t1 ? q1 : bi1;
        }

        if (c == 0) {
            stateBuf[p ^ 1][j]      = bv0 + xa0;
            stateBuf[p ^ 1][j + 64] = bv1 + xa1;
            bp[t][j]      = (unsigned char)bi0;
            bp[t][j + 64] = (unsigned char)bi1;
        }
        xa0 = xb0; xa1 = xb1; xb0 = xc0; xb1 = xc1;
        __syncthreads();
        p ^= 1;
    }

    // Final argmax over state (first-occurrence: min index on ties).
    if (tid < NN) { redV[tid] = stateBuf[p][tid]; redI[tid] = tid; }
    __syncthreads();
    #pragma unroll
    for (int off = 64; off >= 1; off >>= 1) {
        if (tid < off) {
            float va = redV[tid], vb = redV[tid + off];
            int   ia = redI[tid], ib = redI[tid + off];
            if (vb > va || (vb == va && ib < ia)) { redV[tid] = vb; redI[tid] = ib; }
        }
        __syncthreads();
    }

    // ---- Parallel backtrack via chunked function composition ----
    // bp rows t = 1..M. Chunk g covers t in [max(1, th-BD+1), th], th = M-g*BD,
    // processed descending; hist[g][d][s] = tag at position th-1-d given
    // tags[th] = s.
    const int M = L - 1;
    const int G = (M + BD - 1) / BD;   // 0..8

    {   // pass 1: chase all 128 entry tags through two chunks per thread
        int s  = tid & 127;
        int gA = tid >> 7;        // 0..3
        int gB = gA + 4;          // 4..7
        int thA = M - gA * BD,            thB = M - gB * BD;
        int dA  = (gA < G) ? ((thA < BD) ? thA : BD) : 0;
        int dB  = (gB < G) ? ((thB < BD) ? thB : BD) : 0;
        int curA = s, curB = s;
        int maxd = (dA > dB) ? dA : dB;
        for (int d = 0; d < maxd; ++d) {
            if (d < dA) { curA = bp[thA - d][curA]; hist[gA][d][s] = (unsigned char)curA; }
            if (d < dB) { curB = bp[thB - d][curB]; hist[gB][d][s] = (unsigned char)curB; }
        }
    }
    __syncthreads();

    if (tid == 0) {   // entry-tag scan across chunks (G <= 8 serial lookups)
        int e = redI[0];
        tagBuf[L - 1] = e;
        for (int g = 0; g < G; ++g) {
            entryTag[g] = e;
            if (g + 1 < G) e = hist[g][BD - 1][e];   // chunks < G-1 are full
        }
    }
    __syncthreads();

    {   // pass 2: copy winning histories into tagBuf
        int g = tid >> 6, d = tid & 63;
        if (g < G) {
            int th  = M - g * BD;
            int dep = (th < BD) ? th : BD;
            if (d < dep) {
                int e = entryTag[g];
                tagBuf[th - 1 - d] = hist[g][d][e];
            }
        }
    }
    __syncthreads();

    // Coalesced output: tags for k < L, zeros for the masked tail.
    int* orow = out + (size_t)b * TT;
    orow[tid] = (tid < L) ? tagBuf[tid] : 0;
}

extern "C" void kernel_launch(void* const* d_in, const int* in_sizes, int n_in,
                              void* d_out, int out_size, void* d_ws, size_t ws_size,
                              hipStream_t stream) {
    const float* logits = (const float*)d_in[0];
    const float* trans  = (const float*)d_in[1];
    const int*   seqlen = (const int*)d_in[2];
    int*         out    = (int*)d_out;
    const int B = in_sizes[2];  // 256
    crf_viterbi_kernel<<<B, NTHR, 0, stream>>>(logits, trans, seqlen, out);
}

// Round 4
// 717.737 us; speedup vs baseline: 2.3530x; 2.3530x over previous
//
#include <hip/hip_runtime.h>

#define TT 512   // max sequence length T
#define NN 128   // number of tags N
#define NTHR 512 // 8 waves
#define BD  64   // backtrack chunk depth
#define MAXG 8   // max chunks = ceil((TT-1)/BD)
#define SROW 160 // swizzled state row: 8 chunks x 20 floats (16 used + 4 pad)
#define SW(i) (20 * ((i) >> 4) + ((i) & 15))

// DPP cross-lane (pure VALU, no LDS pipe)
template <int CTRL>
__device__ __forceinline__ int dpp_i(int x) {
    return __builtin_amdgcn_update_dpp(x, x, CTRL, 0xf, 0xf, true);
}
template <int CTRL>
__device__ __forceinline__ float dpp_f(float x) {
    union { float f; int i; } u; u.f = x;
    u.i = dpp_i<CTRL>(u.i);
    return u.f;
}
#define DPP_XOR1 0xB1   // quad_perm [1,0,3,2]
#define DPP_XOR2 0x4E   // quad_perm [2,3,0,1]
#define DPP_MIR7 0x141  // row_half_mirror: lane ^= 7

// One block per batch element (256 blocks <-> 256 CUs).
// thread -> (j, c): j = tid>>3 (serves tags j and j+64), c = tid&7 owns
// i-range [16c, 16c+16). Transitions in VGPRs (32/thread). State double-
// buffered in LDS with stride-20 chunk swizzle: every ds_read_b128 slot's 8
// distinct addresses land on 8 distinct bank-quads (conflict-free, static
// offsets -> no scratch). Octet argmax combine is all-DPP. One barrier/step.
__global__ __launch_bounds__(NTHR, 1)
void crf_viterbi_kernel(const float* __restrict__ logits,
                        const float* __restrict__ trans,
                        const int* __restrict__ seqlen,
                        int* __restrict__ out) {
    __shared__ float stateBuf[2][SROW];
    __shared__ float redV[NN];
    __shared__ int   redI[NN];
    __shared__ int   tagBuf[TT];
    __shared__ int   entryTag[MAXG];
    __shared__ unsigned char bp[TT][NN];          // 64 KiB backpointers
    __shared__ unsigned char hist[MAXG][BD][NN];  // 64 KiB backtrack histories

    const int tid = threadIdx.x;
    const int j   = tid >> 3;   // 0..63 (serves j and j+64)
    const int c   = tid & 7;    // i-chunk
    const int i0  = c << 4;
    const int b   = blockIdx.x;
    const int L   = seqlen[b];  // in [1, TT]

    // Transition chunks: tr0[k] = trans[i0+k][j], tr1[k] = trans[i0+k][j+64]
    float tr0[16], tr1[16];
    #pragma unroll
    for (int k = 0; k < 16; ++k) {
        tr0[k] = trans[(i0 + k) * NN + j];
        tr1[k] = trans[(i0 + k) * NN + j + 64];
    }

    const float* lrow = logits + (size_t)b * TT * NN;

    // t = 0 init (swizzled layout)
    if (c < 2) {
        int jj = j + (c << 6);
        stateBuf[0][SW(jj)] = lrow[jj];
    }
    __syncthreads();

    // 1-deep logits prefetch (rows up to TT always allocated)
    float xa0 = lrow[NN + j], xa1 = lrow[NN + j + 64];

    int p = 0;
    for (int t = 1; t < L; ++t) {
        int tn = (t + 1 < L) ? (t + 1) : (L - 1);
        const float* lp = lrow + tn * NN;
        float xb0 = lp[j];
        float xb1 = lp[j + 64];

        // 4 static-offset conflict-free b128 reads of this thread's chunk
        const float* st = stateBuf[p] + 20 * c;
        float4 a0 = *(const float4*)(st);
        float4 a1 = *(const float4*)(st + 4);
        float4 a2 = *(const float4*)(st + 8);
        float4 a3 = *(const float4*)(st + 12);
        float ss[16] = {a0.x, a0.y, a0.z, a0.w, a1.x, a1.y, a1.z, a1.w,
                        a2.x, a2.y, a2.z, a2.w, a3.x, a3.y, a3.z, a3.w};

        float sc0[16], sc1[16];
        #pragma unroll
        for (int k = 0; k < 16; ++k) {
            sc0[k] = ss[k] + tr0[k];
            sc1[k] = ss[k] + tr1[k];
        }

        // In-thread argmax trees, contiguous pairing: take right only if
        // strictly greater == exact jnp first-occurrence semantics.
        float va0[8], va1[8]; int ia0[8], ia1[8];
        #pragma unroll
        for (int k = 0; k < 8; ++k) {
            bool g0 = sc0[2*k+1] > sc0[2*k];
            va0[k] = g0 ? sc0[2*k+1] : sc0[2*k];
            ia0[k] = g0 ? (2*k+1) : (2*k);
            bool g1 = sc1[2*k+1] > sc1[2*k];
            va1[k] = g1 ? sc1[2*k+1] : sc1[2*k];
            ia1[k] = g1 ? (2*k+1) : (2*k);
        }
        #pragma unroll
        for (int w = 4; w >= 1; w >>= 1) {
            #pragma unroll
            for (int k = 0; k < w; ++k) {
                bool g0 = va0[2*k+1] > va0[2*k];
                va0[k] = g0 ? va0[2*k+1] : va0[2*k];
                ia0[k] = g0 ? ia0[2*k+1] : ia0[2*k];
                bool g1 = va1[2*k+1] > va1[2*k];
                va1[k] = g1 ? va1[2*k+1] : va1[2*k];
                ia1[k] = g1 ? ia1[2*k+1] : ia1[2*k];
            }
        }
        float bv0 = va0[0], bv1 = va1[0];
        int   bi0 = i0 + ia0[0], bi1 = i0 + ia1[0];

        // All-DPP octet combine; tie -> lower chunk wins (partner lower iff
        // c&mask). Stage 3 uses row_half_mirror (lane^7): after stages 1,2
        // each quad is uniform, so ^7 is an exact quad-pair exchange.
        #define MERGE_STAGE(CTRL, LOWER)                                   \
        {                                                                  \
            float p0 = dpp_f<CTRL>(bv0); int q0 = dpp_i<CTRL>(bi0);        \
            float p1 = dpp_f<CTRL>(bv1); int q1 = dpp_i<CTRL>(bi1);        \
            bool lower = (LOWER);                                          \
            bool t0 = (p0 > bv0) || (p0 == bv0 && lower);                  \
            bool t1 = (p1 > bv1) || (p1 == bv1 && lower);                  \
            bv0 = t0 ? p0 : bv0; bi0 = t0 ? q0 : bi0;                      \
            bv1 = t1 ? p1 : bv1; bi1 = t1 ? q1 : bi1;                      \
        }
        MERGE_STAGE(DPP_XOR1, (c & 1) != 0)
        MERGE_STAGE(DPP_XOR2, (c & 2) != 0)
        MERGE_STAGE(DPP_MIR7, (c & 4) != 0)
        #undef MERGE_STAGE

        if (c < 2) {   // both quads hold valid results; c=0 writes j, c=1 j+64
            int   jj = j + (c << 6);
            float bv = c ? bv1 : bv0;
            int   bi = c ? bi1 : bi0;
            float xx = c ? xa1 : xa0;
            stateBuf[p ^ 1][SW(jj)] = bv + xx;
            bp[t][jj] = (unsigned char)bi;
        }
        xa0 = xb0; xa1 = xb1;
        __syncthreads();
        p ^= 1;
    }

    // Final argmax over state (first-occurrence: min index on ties).
    if (tid < NN) { redV[tid] = stateBuf[p][SW(tid)]; redI[tid] = tid; }
    __syncthreads();
    #pragma unroll
    for (int off = 64; off >= 1; off >>= 1) {
        if (tid < off) {
            float va = redV[tid], vb = redV[tid + off];
            int   ia = redI[tid], ib = redI[tid + off];
            if (vb > va || (vb == va && ib < ia)) { redV[tid] = vb; redI[tid] = ib; }
        }
        __syncthreads();
    }

    // ---- Parallel backtrack via chunked function composition ----
    const int M = L - 1;
    const int G = (M + BD - 1) / BD;   // 0..8

    {   // pass 1: chase all 128 entry tags through two chunks per thread
        int s  = tid & 127;
        int gA = tid >> 7;        // 0..3
        int gB = gA + 4;          // 4..7
        int thA = M - gA * BD,            thB = M - gB * BD;
        int dA  = (gA < G) ? ((thA < BD) ? thA : BD) : 0;
        int dB  = (gB < G) ? ((thB < BD) ? thB : BD) : 0;
        int curA = s, curB = s;
        int maxd = (dA > dB) ? dA : dB;
        for (int d = 0; d < maxd; ++d) {
            if (d < dA) { curA = bp[thA - d][curA]; hist[gA][d][s] = (unsigned char)curA; }
            if (d < dB) { curB = bp[thB - d][curB]; hist[gB][d][s] = (unsigned char)curB; }
        }
    }
    __syncthreads();

    if (tid == 0) {   // entry-tag scan across chunks (G <= 8 serial lookups)
        int e = redI[0];
        tagBuf[L - 1] = e;
        for (int g = 0; g < G; ++g) {
            entryTag[g] = e;
            if (g + 1 < G) e = hist[g][BD - 1][e];   // chunks < G-1 are full
        }
    }
    __syncthreads();

    {   // pass 2: copy winning histories into tagBuf
        int g = tid >> 6, d = tid & 63;
        if (g < G) {
            int th  = M - g * BD;
            int dep = (th < BD) ? th : BD;
            if (d < dep) {
                int e = entryTag[g];
                tagBuf[th - 1 - d] = hist[g][d][e];
            }
        }
    }
    __syncthreads();

    // Coalesced output: tags for k < L, zeros for the masked tail.
    int* orow = out + (size_t)b * TT;
    orow[tid] = (tid < L) ? tagBuf[tid] : 0;
}

extern "C" void kernel_launch(void* const* d_in, const int* in_sizes, int n_in,
                              void* d_out, int out_size, void* d_ws, size_t ws_size,
                              hipStream_t stream) {
    const float* logits = (const float*)d_in[0];
    const float* trans  = (const float*)d_in[1];
    const int*   seqlen = (const int*)d_in[2];
    int*         out    = (int*)d_out;
    const int B = in_sizes[2];  // 256
    crf_viterbi_kernel<<<B, NTHR, 0, stream>>>(logits, trans, seqlen, out);
}

// Round 5
// 490.659 us; speedup vs baseline: 3.4420x; 1.4628x over previous
//
#include <hip/hip_runtime.h>

#define TT 512   // max sequence length T
#define NN 128   // number of tags N
#define NTHR 512 // 8 waves
#define BD  64   // backtrack chunk depth
#define MAXG 8   // max chunks = ceil((TT-1)/BD)
#define SROW 160 // swizzled state row: 8 chunks x 20 floats (16 used + 4 pad)
#define SW(i) (20 * ((i) >> 4) + ((i) & 15))

// DPP cross-lane (pure VALU, no LDS pipe)
template <int CTRL>
__device__ __forceinline__ int dpp_i(int x) {
    return __builtin_amdgcn_update_dpp(x, x, CTRL, 0xf, 0xf, true);
}
template <int CTRL>
__device__ __forceinline__ float dpp_f(float x) {
    union { float f; int i; } u; u.f = x;
    u.i = dpp_i<CTRL>(u.i);
    return u.f;
}
#define DPP_XOR1 0xB1   // quad_perm [1,0,3,2]
#define DPP_XOR2 0x4E   // quad_perm [2,3,0,1]
#define DPP_MIR7 0x141  // row_half_mirror: lane ^= 7 (exact after stages 1,2)

// One block per batch element (256 blocks <-> 256 CUs).
// thread -> (j, c): j = tid>>3 (serves tags j and j+64), c = tid&7 owns
// i-range [16c, 16c+16). Transitions in VGPRs (32/thread). State double-
// buffered in LDS with stride-20 chunk swizzle (conflict-free static offsets).
// Streaming linear argmax scan with scalar running (best,arg) -> small live
// set, no array rematerialization (the R4 regression). All-DPP octet merge.
// One barrier/step. Parallel chunked backtrack.
__global__ __launch_bounds__(NTHR, 1)
void crf_viterbi_kernel(const float* __restrict__ logits,
                        const float* __restrict__ trans,
                        const int* __restrict__ seqlen,
                        int* __restrict__ out) {
    __shared__ float stateBuf[2][SROW];
    __shared__ float redV[NN];
    __shared__ int   redI[NN];
    __shared__ int   tagBuf[TT];
    __shared__ int   entryTag[MAXG];
    __shared__ unsigned char bp[TT][NN];          // 64 KiB backpointers
    __shared__ unsigned char hist[MAXG][BD][NN];  // 64 KiB backtrack histories

    const int tid = threadIdx.x;
    const int j   = tid >> 3;   // 0..63 (serves j and j+64)
    const int c   = tid & 7;    // i-chunk
    const int i0  = c << 4;
    const int b   = blockIdx.x;
    const int L   = seqlen[b];  // in [1, TT]

    // Transition chunks: tr0[k] = trans[i0+k][j], tr1[k] = trans[i0+k][j+64]
    float tr0[16], tr1[16];
    #pragma unroll
    for (int k = 0; k < 16; ++k) {
        tr0[k] = trans[(i0 + k) * NN + j];
        tr1[k] = trans[(i0 + k) * NN + j + 64];
    }

    const float* lrow = logits + (size_t)b * TT * NN;

    // t = 0 init (swizzled layout)
    if (c < 2) {
        int jj = j + (c << 6);
        stateBuf[0][SW(jj)] = lrow[jj];
    }
    __syncthreads();

    // 1-deep logits prefetch (rows up to TT always allocated)
    float xa0 = lrow[NN + j], xa1 = lrow[NN + j + 64];

    int p = 0;
    for (int t = 1; t < L; ++t) {
        int tn = (t + 1 < L) ? (t + 1) : (L - 1);
        const float* lp = lrow + tn * NN;
        float xb0 = lp[j];
        float xb1 = lp[j + 64];

        // 4 static-offset conflict-free b128 reads of this thread's chunk
        const float* st = stateBuf[p] + 20 * c;
        float4 a0 = *(const float4*)(st);
        float4 a1 = *(const float4*)(st + 4);
        float4 a2 = *(const float4*)(st + 8);
        float4 a3 = *(const float4*)(st + 12);

        // Streaming scan, strict > over ascending k == first-occurrence.
        // Two independent chains (tag0, tag1) give ILP; live set stays tiny.
        float best0 = -__builtin_inff(), best1 = -__builtin_inff();
        int arg0 = 0, arg1 = 0;
        #define ELEM(S, K)                                                  \
        {                                                                   \
            float sc = (S) + tr0[K];                                        \
            bool g = sc > best0; best0 = g ? sc : best0; arg0 = g ? (K) : arg0; \
            float sd = (S) + tr1[K];                                        \
            bool h = sd > best1; best1 = h ? sd : best1; arg1 = h ? (K) : arg1; \
        }
        ELEM(a0.x, 0)  ELEM(a0.y, 1)  ELEM(a0.z, 2)  ELEM(a0.w, 3)
        ELEM(a1.x, 4)  ELEM(a1.y, 5)  ELEM(a1.z, 6)  ELEM(a1.w, 7)
        ELEM(a2.x, 8)  ELEM(a2.y, 9)  ELEM(a2.z, 10) ELEM(a2.w, 11)
        ELEM(a3.x, 12) ELEM(a3.y, 13) ELEM(a3.z, 14) ELEM(a3.w, 15)
        #undef ELEM

        float bv0 = best0, bv1 = best1;
        int   bi0 = i0 + arg0, bi1 = i0 + arg1;

        // All-DPP octet combine; tie -> lower chunk wins.
        #define MERGE_STAGE(CTRL, LOWER)                                   \
        {                                                                  \
            float p0 = dpp_f<CTRL>(bv0); int q0 = dpp_i<CTRL>(bi0);        \
            float p1 = dpp_f<CTRL>(bv1); int q1 = dpp_i<CTRL>(bi1);        \
            bool lower = (LOWER);                                          \
            bool t0 = (p0 > bv0) || (p0 == bv0 && lower);                  \
            bool t1 = (p1 > bv1) || (p1 == bv1 && lower);                  \
            bv0 = t0 ? p0 : bv0; bi0 = t0 ? q0 : bi0;                      \
            bv1 = t1 ? p1 : bv1; bi1 = t1 ? q1 : bi1;                      \
        }
        MERGE_STAGE(DPP_XOR1, (c & 1) != 0)
        MERGE_STAGE(DPP_XOR2, (c & 2) != 0)
        MERGE_STAGE(DPP_MIR7, (c & 4) != 0)
        #undef MERGE_STAGE

        if (c < 2) {   // both quads hold valid results; c=0 writes j, c=1 j+64
            int   jj = j + (c << 6);
            float bv = c ? bv1 : bv0;
            int   bi = c ? bi1 : bi0;
            float xx = c ? xa1 : xa0;
            stateBuf[p ^ 1][SW(jj)] = bv + xx;
            bp[t][jj] = (unsigned char)bi;
        }
        xa0 = xb0; xa1 = xb1;
        __syncthreads();
        p ^= 1;
    }

    // Final argmax over state (first-occurrence: min index on ties).
    if (tid < NN) { redV[tid] = stateBuf[p][SW(tid)]; redI[tid] = tid; }
    __syncthreads();
    #pragma unroll
    for (int off = 64; off >= 1; off >>= 1) {
        if (tid < off) {
            float va = redV[tid], vb = redV[tid + off];
            int   ia = redI[tid], ib = redI[tid + off];
            if (vb > va || (vb == va && ib < ia)) { redV[tid] = vb; redI[tid] = ib; }
        }
        __syncthreads();
    }

    // ---- Parallel backtrack via chunked function composition ----
    const int M = L - 1;
    const int G = (M + BD - 1) / BD;   // 0..8

    {   // pass 1: chase all 128 entry tags through two chunks per thread
        int s  = tid & 127;
        int gA = tid >> 7;        // 0..3
        int gB = gA + 4;          // 4..7
        int thA = M - gA * BD,            thB = M - gB * BD;
        int dA  = (gA < G) ? ((thA < BD) ? thA : BD) : 0;
        int dB  = (gB < G) ? ((thB < BD) ? thB : BD) : 0;
        int curA = s, curB = s;
        int maxd = (dA > dB) ? dA : dB;
        for (int d = 0; d < maxd; ++d) {
            if (d < dA) { curA = bp[thA - d][curA]; hist[gA][d][s] = (unsigned char)curA; }
            if (d < dB) { curB = bp[thB - d][curB]; hist[gB][d][s] = (unsigned char)curB; }
        }
    }
    __syncthreads();

    if (tid == 0) {   // entry-tag scan across chunks (G <= 8 serial lookups)
        int e = redI[0];
        tagBuf[L - 1] = e;
        for (int g = 0; g < G; ++g) {
            entryTag[g] = e;
            if (g + 1 < G) e = hist[g][BD - 1][e];   // chunks < G-1 are full
        }
    }
    __syncthreads();

    {   // pass 2: copy winning histories into tagBuf
        int g = tid >> 6, d = tid & 63;
        if (g < G) {
            int th  = M - g * BD;
            int dep = (th < BD) ? th : BD;
            if (d < dep) {
                int e = entryTag[g];
                tagBuf[th - 1 - d] = hist[g][d][e];
            }
        }
    }
    __syncthreads();

    // Coalesced output: tags for k < L, zeros for the masked tail.
    int* orow = out + (size_t)b * TT;
    orow[tid] = (tid < L) ? tagBuf[tid] : 0;
}

extern "C" void kernel_launch(void* const* d_in, const int* in_sizes, int n_in,
                              void* d_out, int out_size, void* d_ws, size_t ws_size,
                              hipStream_t stream) {
    const float* logits = (const float*)d_in[0];
    const float* trans  = (const float*)d_in[1];
    const int*   seqlen = (const int*)d_in[2];
    int*         out    = (int*)d_out;
    const int B = in_sizes[2];  // 256
    crf_viterbi_kernel<<<B, NTHR, 0, stream>>>(logits, trans, seqlen, out);
}